// Round 11
// baseline (150.755 us; speedup 1.0000x reference)
//
#include <hip/hip_runtime.h>
#include <hip/hip_fp16.h>
#include <stdint.h>

#define IN_F 8192
#define OUT_F 8192
#define NGROUPS 64
#define QW_COLS 1024   // IN_F/8 packed int32 per output row
#define QZ_COLS 8
#define M_TOTAL 128
#define BN 256
#define KSPLIT 16
#define KRANGE (IN_F / KSPLIT)  // 512
#define BK 32
#define NITER (KRANGE / BK)     // 16
#define NTILES (OUT_F / BN)     // 32
#define K16S (IN_F / 16)        // 512

typedef _Float16 half8 __attribute__((ext_vector_type(8)));
typedef float floatx16 __attribute__((ext_vector_type(16)));

typedef __attribute__((address_space(3))) uint32_t* lds_u32p;
typedef const __attribute__((address_space(1))) uint32_t* glb_u32p;

// async 16B/lane global->LDS; LDS dest = uniform base + lane*16
__device__ inline void gl_lds16(const uint16_t* g, uint16_t* l) {
  __builtin_amdgcn_global_load_lds((glb_u32p)g, (lds_u32p)l, 16, 0, 0);
}

// Dequant one packed word (8 nibbles) -> 8 f16 in k-order, bit-identical to ref.
__device__ inline uint4 dq_word(uint32_t w, uint32_t hz2u, uint32_t s2u) {
  const __half2 hz2 = __builtin_bit_cast(__half2, hz2u);
  const __half2 s2 = __builtin_bit_cast(__half2, s2u);
  uint32_t r[4];
#pragma unroll
  for (int p = 0; p < 4; ++p) {
    uint32_t t = ((w >> (4 * p)) & 0x000F000Fu) | 0x64006400u;
    __half2 v = __hmul2(__hsub2(__builtin_bit_cast(__half2, t), hz2), s2);
    r[p] = __builtin_bit_cast(uint32_t, v);  // (elem p, elem p+4)
  }
  uint4 o;
  o.x = (r[0] & 0xFFFFu) | (r[1] << 16);
  o.y = (r[2] & 0xFFFFu) | (r[3] << 16);
  o.z = (r[0] >> 16) | (r[1] & 0xFFFF0000u);
  o.w = (r[2] >> 16) | (r[3] & 0xFFFF0000u);
  return o;
}

// dequant this thread's 4 words (one col, full BK=32) into B fragment buffer.
// word i -> ks = i>>1, hf = i&1; dst = bOff + ((i>>1)*64 + (i&1)*32)*8
__device__ inline void dq4_to_lds(uint4 q, float sf, uint32_t z, uint16_t* bbuf,
                                  int bOff) {
  const uint32_t hz2u = 0x64006400u | z | (z << 16);
  const uint16_t hs = __builtin_bit_cast(uint16_t, __float2half(sf));
  const uint32_t s2u = (uint32_t)hs | ((uint32_t)hs << 16);
  const uint32_t w[4] = {q.x, q.y, q.z, q.w};
#pragma unroll
  for (int i = 0; i < 4; ++i) {
    uint4 v = dq_word(w[i], hz2u, s2u);
    *(uint4*)(bbuf + bOff + (((i >> 1) * 64 + (i & 1) * 32) * 8)) = v;
  }
}

// wave tile 128x64 (4 mblk x 2 nblk acc). 4 waves -> BN=256. 2 blocks/CU.
__global__ __launch_bounds__(256, 2) void awq_fast(
    const uint16_t* __restrict__ aT, const int* __restrict__ qweight,
    const float* __restrict__ scales, const int* __restrict__ qzeros,
    float* __restrict__ out) {
  // fragment-major double buffers: chunk -> 64 lanes x 8 halves (1 KiB)
  __shared__ uint16_t aL[2][8 * 512];   // A: 4 mblk x 2 k16 = 8 KiB per buf
  __shared__ uint16_t bL[2][16 * 512];  // B: 8 nblk x 2 ks  = 16 KiB per buf

  const int tid = threadIdx.x;
  const int bx = blockIdx.x;
  const int ntile = bx & (NTILES - 1);
  const int kslice = bx >> 5;          // 0..15
  const int n0 = ntile * BN;

  const int lane = tid & 63;
  const int wave = tid >> 6;           // 0..3; nblk pair {2w, 2w+1}
  const int l31 = lane & 31;
  const int half = lane >> 5;

  floatx16 acc[4][2] = {};  // [mblk][nblk-local]

  // dequant role: one col per thread
  const long long col = n0 + tid;
  const long long wbase = col * QW_COLS + kslice * 64;  // KRANGE/8 = 64 words
  const int bOff = (((tid >> 5) * 2) * 64 + (tid & 31)) * 8;

  // kslice covers groups kslice*4 .. +3
  const float4 s4 = *(const float4*)(scales + col * NGROUPS + kslice * 4);
  const float sarr[4] = {s4.x, s4.y, s4.z, s4.w};
  const uint32_t zword = (uint32_t)qzeros[col * QZ_COLS + (kslice >> 1)];
  const int zsh = (kslice & 1) * 16;

  // qweight register pipeline (distance 3): q[it] = uint4 at wbase + it*4
  uint4 q0 = *(const uint4*)(qweight + wbase);
  uint4 qs[3];
  qs[1] = *(const uint4*)(qweight + wbase + 4);   // q[1]
  qs[2] = *(const uint4*)(qweight + wbase + 8);   // q[2]
  qs[0] = *(const uint4*)(qweight + wbase + 12);  // q[3]

  // A staging: 8 chunks (mblk*2 + k16r), wave stages chunks 2w, 2w+1
  const int c0 = 2 * wave;

  // pre-loop: stage A(0) + dequant q[0] into buf 0
  {
#pragma unroll
    for (int i = 0; i < 2; ++i) {
      const int c = c0 + i;
      gl_lds16(aT + (((long long)(c >> 1) * K16S + kslice * 32 + (c & 1)) * 64 + lane) * 8,
               &aL[0][c * 512]);
    }
    dq4_to_lds(q0, sarr[0], (zword >> zsh) & 0xFu, bL[0], bOff);
  }

#pragma unroll
  for (int it = 0; it < NITER; ++it) {
    const int pb = it & 1;
    const int pn = pb ^ 1;
    __syncthreads();  // drains buf[pb] A-DMAs (vmcnt) + B ds_writes (lgkm)

    if (it + 1 < NITER) {
      // async A-stage for it+1 (flies under this iter's MFMA)
#pragma unroll
      for (int i = 0; i < 2; ++i) {
        const int c = c0 + i;
        gl_lds16(aT + (((long long)(c >> 1) * K16S + kslice * 32 + (it + 1) * 2 +
                        (c & 1)) * 64 + lane) * 8,
                 &aL[pn][c * 512]);
      }
      // dequant q[it+1] -> buf pn
      const int gl = (it + 1) >> 2;  // group within slice
      const uint32_t z = (zword >> (zsh + gl * 4)) & 0xFu;
      dq4_to_lds(qs[(it + 1) % 3], sarr[gl], z, bL[pn], bOff);
      // refill consumed slot with q[it+4]
      if (it + 4 < NITER)
        qs[(it + 1) % 3] = *(const uint4*)(qweight + wbase + (it + 4) * 4);
    }

    // MFMA phase on buf pb: 2 k16-steps x (4 mblk x 2 nblk)
#pragma unroll
    for (int ks = 0; ks < 2; ++ks) {
      half8 b0 = *(const half8*)(&bL[pb][((2 * wave) * 2 + ks) * 512 + lane * 8]);
      half8 b1 = *(const half8*)(&bL[pb][((2 * wave + 1) * 2 + ks) * 512 + lane * 8]);
#pragma unroll
      for (int im = 0; im < 4; ++im) {
        half8 a = *(const half8*)(&aL[pb][(im * 2 + ks) * 512 + lane * 8]);
        acc[im][0] = __builtin_amdgcn_mfma_f32_32x32x16_f16(a, b0, acc[im][0], 0, 0, 0);
        acc[im][1] = __builtin_amdgcn_mfma_f32_32x32x16_f16(a, b1, acc[im][1], 0, 0, 0);
      }
    }
  }

  // epilogue: K-split partials into bias-pre-initialized out (device atomics).
  // C/D 32x32: col=lane&31, row=(reg&3)+8*(reg>>2)+4*(lane>>5)
#pragma unroll
  for (int im = 0; im < 4; ++im)
#pragma unroll
    for (int in2 = 0; in2 < 2; ++in2) {
      const int n = n0 + (2 * wave + in2) * 32 + l31;
#pragma unroll
      for (int reg = 0; reg < 16; ++reg) {
        const int m = im * 32 + (reg & 3) + 8 * (reg >> 2) + 4 * half;
        atomicAdd(out + (long long)m * OUT_F + n, acc[im][in2][reg]);
      }
    }
}

// prologue: aT = f16(x) fragment-major:
// aT[mblk][k16][hf*32+l31][j] = x[mblk*32 + l31][k16*16 + hf*8 + j]
__global__ __launch_bounds__(256) void prologue(const float* __restrict__ x,
                                                uint16_t* __restrict__ aT) {
  const int t = blockIdx.x * 256 + threadIdx.x;
  const int idx = t * 8;
  const int row = idx >> 13;
  const int col = idx & (IN_F - 1);

  float4 v0 = *(const float4*)(x + idx);
  float4 v1 = *(const float4*)(x + idx + 4);
  union { uint16_t h[8]; uint4 v; } r;
  r.h[0] = __builtin_bit_cast(uint16_t, __float2half(v0.x));
  r.h[1] = __builtin_bit_cast(uint16_t, __float2half(v0.y));
  r.h[2] = __builtin_bit_cast(uint16_t, __float2half(v0.z));
  r.h[3] = __builtin_bit_cast(uint16_t, __float2half(v0.w));
  r.h[4] = __builtin_bit_cast(uint16_t, __float2half(v1.x));
  r.h[5] = __builtin_bit_cast(uint16_t, __float2half(v1.y));
  r.h[6] = __builtin_bit_cast(uint16_t, __float2half(v1.z));
  r.h[7] = __builtin_bit_cast(uint16_t, __float2half(v1.w));

  const int mblk = row >> 5;
  const int l31r = row & 31;
  const int k16 = col >> 4;
  const int hf = (col >> 3) & 1;
  const long long dst = (((long long)mblk * K16S + k16) * 64 + hf * 32 + l31r) * 8;
  *(uint4*)(aT + dst) = r.v;
}

__global__ __launch_bounds__(256) void init_out(const float* __restrict__ bias,
                                                float* __restrict__ out) {
  int idx = (blockIdx.x * 256 + threadIdx.x) * 4;
  float4 b = *(const float4*)(bias + (idx & (OUT_F - 1)));
  *(float4*)(out + idx) = b;
}

// low fallback (no workspace): f32 x reads, single-buffer LDS, atomics.
#define FB_NTILES 64
__global__ __launch_bounds__(256) void awq_fallback(
    const float* __restrict__ xf32, const int* __restrict__ qweight,
    const float* __restrict__ scales, const int* __restrict__ qzeros,
    float* __restrict__ out) {
  __shared__ uint16_t bT[4 * 8 * 64 * 8];  // 32 KiB

  const int tid = threadIdx.x;
  const int bx = blockIdx.x;
  const int ntile = bx & (FB_NTILES - 1);
  const int kslice = bx >> 6;  // 0..7
  const int n0 = ntile * 128;
  const int kbase = kslice * 1024;

  const int lane = tid & 63;
  const int wave = tid >> 6;
  const int mw = wave >> 1;
  const int nw = wave & 1;
  const int l31 = lane & 31;
  const int half = lane >> 5;

  floatx16 acc[2][2] = {};

  const int wcol = tid >> 1;
  const int wh = tid & 1;
  const long long qw_base = (long long)(n0 + wcol) * QW_COLS + (kbase >> 3) + wh * 8;
  const long long sc_base = (long long)(n0 + wcol) * NGROUPS;
  const long long qz_base = (long long)(n0 + wcol) * QZ_COLS;
  const int bOff = ((wcol >> 5) * 8 * 64 + (wcol & 31)) * 8;

  const long long arow0 = (long long)(mw * 64 + l31) * IN_F + half * 8;
  const long long arow1 = (long long)(mw * 64 + 32 + l31) * IN_F + half * 8;

  for (int it = 0; it < 8; ++it) {
    const int g = kslice * 8 + it;
    const float sf = scales[sc_base + g];
    const int zw = qzeros[qz_base + (g >> 3)];
    const uint32_t z = (uint32_t)(zw >> ((g & 7) * 4)) & 0xFu;
    const uint32_t hz2u = 0x64006400u | z | (z << 16);
    const uint16_t hs = __builtin_bit_cast(uint16_t, __float2half(sf));
    const uint32_t s2u = (uint32_t)hs | ((uint32_t)hs << 16);
    uint4 q0 = *(const uint4*)(qweight + qw_base + it * 16);
    uint4 q1 = *(const uint4*)(qweight + qw_base + it * 16 + 4);

    if (it > 0) __syncthreads();
    const uint32_t w[8] = {q0.x, q0.y, q0.z, q0.w, q1.x, q1.y, q1.z, q1.w};
#pragma unroll
    for (int i = 0; i < 8; ++i) {
      uint4 v = dq_word(w[i], hz2u, s2u);
      *(uint4*)(&bT[bOff + (((wh * 4 + (i >> 1)) * 64 + (i & 1) * 32) * 8)]) = v;
    }
    __syncthreads();

#pragma unroll
    for (int ks = 0; ks < 8; ++ks) {
      const int ko = kbase + it * 128 + ks * 16;
      float4 f0 = *(const float4*)(xf32 + arow0 + ko);
      float4 f1 = *(const float4*)(xf32 + arow0 + ko + 4);
      half8 a0 = half8{(_Float16)f0.x, (_Float16)f0.y, (_Float16)f0.z, (_Float16)f0.w,
                       (_Float16)f1.x, (_Float16)f1.y, (_Float16)f1.z, (_Float16)f1.w};
      float4 g0 = *(const float4*)(xf32 + arow1 + ko);
      float4 g1 = *(const float4*)(xf32 + arow1 + ko + 4);
      half8 a1 = half8{(_Float16)g0.x, (_Float16)g0.y, (_Float16)g0.z, (_Float16)g0.w,
                       (_Float16)g1.x, (_Float16)g1.y, (_Float16)g1.z, (_Float16)g1.w};
      half8 b0 = *(const half8*)(&bT[((nw * 2) * 8 * 64 + ks * 64 + lane) * 8]);
      half8 b1 = *(const half8*)(&bT[((nw * 2 + 1) * 8 * 64 + ks * 64 + lane) * 8]);
      acc[0][0] = __builtin_amdgcn_mfma_f32_32x32x16_f16(a0, b0, acc[0][0], 0, 0, 0);
      acc[0][1] = __builtin_amdgcn_mfma_f32_32x32x16_f16(a0, b1, acc[0][1], 0, 0, 0);
      acc[1][0] = __builtin_amdgcn_mfma_f32_32x32x16_f16(a1, b0, acc[1][0], 0, 0, 0);
      acc[1][1] = __builtin_amdgcn_mfma_f32_32x32x16_f16(a1, b1, acc[1][1], 0, 0, 0);
    }
  }

  const int cn = n0 + nw * 64 + l31;
#pragma unroll
  for (int im = 0; im < 2; ++im)
#pragma unroll
    for (int in2 = 0; in2 < 2; ++in2)
#pragma unroll
      for (int reg = 0; reg < 16; ++reg) {
        int m = mw * 64 + im * 32 + (reg & 3) + 8 * (reg >> 2) + 4 * half;
        atomicAdd(out + (long long)m * OUT_F + cn + in2 * 32, acc[im][in2][reg]);
      }
}

extern "C" void kernel_launch(void* const* d_in, const int* in_sizes, int n_in,
                              void* d_out, int out_size, void* d_ws, size_t ws_size,
                              hipStream_t stream) {
  const float* x = (const float*)d_in[0];
  const int* qw = (const int*)d_in[1];
  const float* sc = (const float*)d_in[2];
  const int* qz = (const int*)d_in[3];
  const float* bias = (const float*)d_in[4];
  float* out = (float*)d_out;
  uint16_t* aT = (uint16_t*)d_ws;

  const size_t aT_bytes = (size_t)M_TOTAL * IN_F * sizeof(uint16_t);  // 2 MiB
  init_out<<<(M_TOTAL * OUT_F) / (256 * 4), 256, 0, stream>>>(bias, out);
  if (ws_size >= aT_bytes) {
    prologue<<<(M_TOTAL * IN_F) / (256 * 8), 256, 0, stream>>>(x, aT);
    awq_fast<<<NTILES * KSPLIT, 256, 0, stream>>>(aT, qw, sc, qz, out);
  } else {
    awq_fallback<<<FB_NTILES * 8, 256, 0, stream>>>(x, qw, sc, qz, out);
  }
}

// Round 12
// 126.502 us; speedup vs baseline: 1.1917x; 1.1917x over previous
//
#include <hip/hip_runtime.h>
#include <hip/hip_fp16.h>
#include <stdint.h>

#define IN_F 8192
#define OUT_F 8192
#define NGROUPS 64
#define QW_COLS 1024   // IN_F/8 packed int32 per output row
#define QZ_COLS 8
#define M_TOTAL 128
#define BN 256
#define KSPLIT 8
#define KRANGE (IN_F / KSPLIT)  // 1024
#define BK 64
#define NITER (KRANGE / BK)     // 16
#define NTILES (OUT_F / BN)     // 32
#define K16S (IN_F / 16)        // 512

typedef _Float16 half8 __attribute__((ext_vector_type(8)));
typedef float floatx16 __attribute__((ext_vector_type(16)));

typedef __attribute__((address_space(3))) uint32_t* lds_u32p;
typedef const __attribute__((address_space(1))) uint32_t* glb_u32p;

// async 16B/lane global->LDS; LDS dest = uniform base + lane*16
__device__ inline void gl_lds16(const uint16_t* g, uint16_t* l) {
  __builtin_amdgcn_global_load_lds((glb_u32p)g, (lds_u32p)l, 16, 0, 0);
}

// Dequant one packed word (8 nibbles) -> 8 f16 in k-order, bit-identical to ref.
__device__ inline uint4 dq_word(uint32_t w, uint32_t hz2u, uint32_t s2u) {
  const __half2 hz2 = __builtin_bit_cast(__half2, hz2u);
  const __half2 s2 = __builtin_bit_cast(__half2, s2u);
  uint32_t r[4];
#pragma unroll
  for (int p = 0; p < 4; ++p) {
    uint32_t t = ((w >> (4 * p)) & 0x000F000Fu) | 0x64006400u;
    __half2 v = __hmul2(__hsub2(__builtin_bit_cast(__half2, t), hz2), s2);
    r[p] = __builtin_bit_cast(uint32_t, v);  // (elem p, elem p+4)
  }
  uint4 o;
  o.x = (r[0] & 0xFFFFu) | (r[1] << 16);
  o.y = (r[2] & 0xFFFFu) | (r[3] << 16);
  o.z = (r[0] >> 16) | (r[1] & 0xFFFF0000u);
  o.w = (r[2] >> 16) | (r[3] & 0xFFFF0000u);
  return o;
}

// dequant this thread's 4 words (k-span 32 of BK=64) into B fragment buffer.
// word i -> ks = wh*2 + (i>>1), hf = i&1 (verified R8/R10 mapping)
__device__ inline void dq4_to_lds(const uint32_t w[4], float sf, uint32_t z,
                                  uint16_t* bbuf, int bOff, int wh) {
  const uint32_t hz2u = 0x64006400u | z | (z << 16);
  const uint16_t hs = __builtin_bit_cast(uint16_t, __float2half(sf));
  const uint32_t s2u = (uint32_t)hs | ((uint32_t)hs << 16);
#pragma unroll
  for (int i = 0; i < 4; ++i) {
    uint4 v = dq_word(w[i], hz2u, s2u);
    *(uint4*)(bbuf + bOff + (((wh * 2 + (i >> 1)) * 64 + (i & 1) * 32) * 8)) = v;
  }
}

// R10 geometry + k-major qT (coalesced qweight reads). EPI: streaming partial
// stores; reduce kernel adds bias + sums kslices.
__global__ __launch_bounds__(512, 2) void awq_fast(
    const uint16_t* __restrict__ aT, const uint32_t* __restrict__ qT,
    const float* __restrict__ scales, const int* __restrict__ qzeros,
    float* __restrict__ part) {
  __shared__ uint16_t aL[2][16 * 512];  // A: 4 mblk x 4 k16 = 16 KiB per buf
  __shared__ uint16_t bL[2][32 * 512];  // B: 8 nblk x 4 ks  = 32 KiB per buf

  const int tid = threadIdx.x;
  const int bx = blockIdx.x;
  const int ntile = bx & (NTILES - 1);
  const int kslice = bx >> 5;          // 0..7
  const int n0 = ntile * BN;

  const int lane = tid & 63;
  const int wave = tid >> 6;           // 0..7
  const int mw = wave >> 2;            // 2 m-waves x 4 n-waves; wave tile 64x64
  const int nw = wave & 3;
  const int l31 = lane & 31;
  const int half = lane >> 5;

  floatx16 acc[2][2] = {};

  // dequant role: col = n0 + (tid>>1); wh = tid&1 selects k-half (32) of BK=64
  const int wcol = tid >> 1;
  const int wh = tid & 1;
  const long long col = n0 + wcol;
  const int bOff = (((wcol >> 5) * 4) * 64 + (wcol & 31)) * 8;

  // kslice covers groups kslice*8 .. +7 == exactly one qzeros word
  const float4 sA = *(const float4*)(scales + col * NGROUPS + kslice * 8);
  const float4 sB = *(const float4*)(scales + col * NGROUPS + kslice * 8 + 4);
  const float sarr[8] = {sA.x, sA.y, sA.z, sA.w, sB.x, sB.y, sB.z, sB.w};
  const uint32_t zword = (uint32_t)qzeros[col * QZ_COLS + kslice];

  // qT word address for (iter, j): kw = kslice*128 + iter*8 + wh*4 + j
  const long long qrow0 = ((long long)(kslice * 128 + wh * 4)) * OUT_F + col;
  // lane->col contiguous: each load touches ~4 cache lines (was 32 gather)
#define QLD(it, j) qT[qrow0 + ((long long)(it) * 8 + (j)) * OUT_F]

  // register pipeline distance 2: slot p holds q[i], i&1==p
  uint32_t q0[4], qs[2][4];
#pragma unroll
  for (int j = 0; j < 4; ++j) q0[j] = QLD(0, j);
#pragma unroll
  for (int j = 0; j < 4; ++j) qs[1][j] = QLD(1, j);
#pragma unroll
  for (int j = 0; j < 4; ++j) qs[0][j] = QLD(2, j);

  // A staging: 16 chunks (mblk*4 + k16r); wave stages chunks 2w, 2w+1
  const int c0 = 2 * wave;

  // pre-loop: stage A(0) + dequant q[0] into buf 0
  {
#pragma unroll
    for (int i = 0; i < 2; ++i) {
      const int c = c0 + i;
      gl_lds16(aT + (((long long)(c >> 2) * K16S + kslice * 64 + (c & 3)) * 64 + lane) * 8,
               &aL[0][c * 512]);
    }
    dq4_to_lds(q0, sarr[0], zword & 0xFu, bL[0], bOff, wh);
  }

#pragma unroll
  for (int it = 0; it < NITER; ++it) {
    const int pb = it & 1;
    const int pn = pb ^ 1;
    __syncthreads();  // drains buf[pb] A-DMAs (vmcnt) + B ds_writes (lgkm)

    if (it + 1 < NITER) {
      // async A-stage for it+1 (flies under this iter's MFMA)
#pragma unroll
      for (int i = 0; i < 2; ++i) {
        const int c = c0 + i;
        gl_lds16(aT + (((long long)(c >> 2) * K16S + kslice * 64 + (it + 1) * 4 +
                        (c & 3)) * 64 + lane) * 8,
                 &aL[pn][c * 512]);
      }
      // dequant q[it+1] -> buf pn
      const int gl = (it + 1) >> 1;  // group within slice (BK=64, GROUP=128)
      const uint32_t z = (zword >> (gl * 4)) & 0xFu;
      dq4_to_lds(qs[(it + 1) & 1], sarr[gl], z, bL[pn], bOff, wh);
      // refill consumed slot with q[it+3] (coalesced, drains at next barrier)
      if (it + 3 < NITER) {
#pragma unroll
        for (int j = 0; j < 4; ++j) qs[(it + 1) & 1][j] = QLD(it + 3, j);
      }
    }

    // MFMA phase on buf pb: 4 k16-steps x (2 mblk x 2 nblk)
#pragma unroll
    for (int ks = 0; ks < 4; ++ks) {
      half8 a0 = *(const half8*)(&aL[pb][((2 * mw) * 4 + ks) * 512 + lane * 8]);
      half8 a1 = *(const half8*)(&aL[pb][((2 * mw + 1) * 4 + ks) * 512 + lane * 8]);
      half8 b0 = *(const half8*)(&bL[pb][((2 * nw) * 4 + ks) * 512 + lane * 8]);
      half8 b1 = *(const half8*)(&bL[pb][((2 * nw + 1) * 4 + ks) * 512 + lane * 8]);
      acc[0][0] = __builtin_amdgcn_mfma_f32_32x32x16_f16(a0, b0, acc[0][0], 0, 0, 0);
      acc[0][1] = __builtin_amdgcn_mfma_f32_32x32x16_f16(a0, b1, acc[0][1], 0, 0, 0);
      acc[1][0] = __builtin_amdgcn_mfma_f32_32x32x16_f16(a1, b0, acc[1][0], 0, 0, 0);
      acc[1][1] = __builtin_amdgcn_mfma_f32_32x32x16_f16(a1, b1, acc[1][1], 0, 0, 0);
    }
  }
#undef QLD

  // epilogue: streaming stores to per-kslice partials.
  // C/D 32x32: col=lane&31, row=(reg&3)+8*(reg>>2)+4*(lane>>5)
#pragma unroll
  for (int im = 0; im < 2; ++im)
#pragma unroll
    for (int in2 = 0; in2 < 2; ++in2) {
      const int n = n0 + (2 * nw + in2) * 32 + l31;
#pragma unroll
      for (int reg = 0; reg < 16; ++reg) {
        const int m = (2 * mw + im) * 32 + (reg & 3) + 8 * (reg >> 2) + 4 * half;
        part[((long long)kslice * M_TOTAL + m) * OUT_F + n] = acc[im][in2][reg];
      }
    }
}

// qT[kw][col] = qweight[col][kw], 64x64-dword LDS tiles, coalesced both sides.
__global__ __launch_bounds__(256) void transpose_qw(
    const uint32_t* __restrict__ qw, uint32_t* __restrict__ qT) {
  __shared__ uint32_t tile[64][65];
  const int bidC = blockIdx.x & 127;  // 128 col-tiles
  const int bidK = blockIdx.x >> 7;   // 16 kw-tiles
  const int col0 = bidC * 64;
  const int kw0 = bidK * 64;
  const int tl = threadIdx.x & 63;
  const int tg = threadIdx.x >> 6;  // 0..3
#pragma unroll
  for (int j = 0; j < 16; ++j) {
    const int c = j * 4 + tg;
    tile[tl][c] = qw[(long long)(col0 + c) * QW_COLS + kw0 + tl];
  }
  __syncthreads();
#pragma unroll
  for (int j = 0; j < 16; ++j) {
    const int r = j * 4 + tg;
    qT[(long long)(kw0 + r) * OUT_F + col0 + tl] = tile[r][tl];
  }
}

// reduce: out = bias + sum over KSPLIT partials
__global__ __launch_bounds__(256) void reduce_out(const float* __restrict__ part,
                                                  const float* __restrict__ bias,
                                                  float* __restrict__ out) {
  const long long idx = ((long long)blockIdx.x * 256 + threadIdx.x) * 4;
  float4 s = *(const float4*)(bias + (idx & (OUT_F - 1)));
#pragma unroll
  for (int k = 0; k < KSPLIT; ++k) {
    float4 p = *(const float4*)(part + (long long)k * M_TOTAL * OUT_F + idx);
    s.x += p.x; s.y += p.y; s.z += p.z; s.w += p.w;
  }
  *(float4*)(out + idx) = s;
}

// prologue: aT = f16(x) fragment-major:
// aT[mblk][k16][hf*32+l31][j] = x[mblk*32 + l31][k16*16 + hf*8 + j]
__global__ __launch_bounds__(256) void prologue(const float* __restrict__ x,
                                                uint16_t* __restrict__ aT) {
  const int t = blockIdx.x * 256 + threadIdx.x;
  const int idx = t * 8;
  const int row = idx >> 13;
  const int col = idx & (IN_F - 1);

  float4 v0 = *(const float4*)(x + idx);
  float4 v1 = *(const float4*)(x + idx + 4);
  union { uint16_t h[8]; uint4 v; } r;
  r.h[0] = __builtin_bit_cast(uint16_t, __float2half(v0.x));
  r.h[1] = __builtin_bit_cast(uint16_t, __float2half(v0.y));
  r.h[2] = __builtin_bit_cast(uint16_t, __float2half(v0.z));
  r.h[3] = __builtin_bit_cast(uint16_t, __float2half(v0.w));
  r.h[4] = __builtin_bit_cast(uint16_t, __float2half(v1.x));
  r.h[5] = __builtin_bit_cast(uint16_t, __float2half(v1.y));
  r.h[6] = __builtin_bit_cast(uint16_t, __float2half(v1.z));
  r.h[7] = __builtin_bit_cast(uint16_t, __float2half(v1.w));

  const int mblk = row >> 5;
  const int l31r = row & 31;
  const int k16 = col >> 4;
  const int hf = (col >> 3) & 1;
  const long long dst = (((long long)mblk * K16S + k16) * 64 + hf * 32 + l31r) * 8;
  *(uint4*)(aT + dst) = r.v;
}

__global__ __launch_bounds__(256) void init_out(const float* __restrict__ bias,
                                                float* __restrict__ out) {
  int idx = (blockIdx.x * 256 + threadIdx.x) * 4;
  float4 b = *(const float4*)(bias + (idx & (OUT_F - 1)));
  *(float4*)(out + idx) = b;
}

// low fallback (small ws): f32 x reads, single-buffer LDS, atomics.
#define FB_NTILES 64
__global__ __launch_bounds__(256) void awq_fallback(
    const float* __restrict__ xf32, const int* __restrict__ qweight,
    const float* __restrict__ scales, const int* __restrict__ qzeros,
    float* __restrict__ out) {
  __shared__ uint16_t bT[4 * 8 * 64 * 8];  // 32 KiB

  const int tid = threadIdx.x;
  const int bx = blockIdx.x;
  const int ntile = bx & (FB_NTILES - 1);
  const int kslice = bx >> 6;  // 0..7
  const int n0 = ntile * 128;
  const int kbase = kslice * 1024;

  const int lane = tid & 63;
  const int wave = tid >> 6;
  const int mw = wave >> 1;
  const int nw = wave & 1;
  const int l31 = lane & 31;
  const int half = lane >> 5;

  floatx16 acc[2][2] = {};

  const int wcol = tid >> 1;
  const int wh = tid & 1;
  const long long qw_base = (long long)(n0 + wcol) * QW_COLS + (kbase >> 3) + wh * 8;
  const long long sc_base = (long long)(n0 + wcol) * NGROUPS;
  const long long qz_base = (long long)(n0 + wcol) * QZ_COLS;
  const int bOff = ((wcol >> 5) * 8 * 64 + (wcol & 31)) * 8;

  const long long arow0 = (long long)(mw * 64 + l31) * IN_F + half * 8;
  const long long arow1 = (long long)(mw * 64 + 32 + l31) * IN_F + half * 8;

  for (int it = 0; it < 8; ++it) {
    const int g = kslice * 8 + it;
    const float sf = scales[sc_base + g];
    const int zw = qzeros[qz_base + (g >> 3)];
    const uint32_t z = (uint32_t)(zw >> ((g & 7) * 4)) & 0xFu;
    const uint32_t hz2u = 0x64006400u | z | (z << 16);
    const uint16_t hs = __builtin_bit_cast(uint16_t, __float2half(sf));
    const uint32_t s2u = (uint32_t)hs | ((uint32_t)hs << 16);
    uint4 q0 = *(const uint4*)(qweight + qw_base + it * 16);
    uint4 q1 = *(const uint4*)(qweight + qw_base + it * 16 + 4);

    if (it > 0) __syncthreads();
    const uint32_t w[8] = {q0.x, q0.y, q0.z, q0.w, q1.x, q1.y, q1.z, q1.w};
#pragma unroll
    for (int i = 0; i < 8; ++i) {
      uint4 v = dq_word(w[i], hz2u, s2u);
      *(uint4*)(&bT[bOff + (((wh * 4 + (i >> 1)) * 64 + (i & 1) * 32) * 8)]) = v;
    }
    __syncthreads();

#pragma unroll
    for (int ks = 0; ks < 8; ++ks) {
      const int ko = kbase + it * 128 + ks * 16;
      float4 f0 = *(const float4*)(xf32 + arow0 + ko);
      float4 f1 = *(const float4*)(xf32 + arow0 + ko + 4);
      half8 a0 = half8{(_Float16)f0.x, (_Float16)f0.y, (_Float16)f0.z, (_Float16)f0.w,
                       (_Float16)f1.x, (_Float16)f1.y, (_Float16)f1.z, (_Float16)f1.w};
      float4 g0 = *(const float4*)(xf32 + arow1 + ko);
      float4 g1 = *(const float4*)(xf32 + arow1 + ko + 4);
      half8 a1 = half8{(_Float16)g0.x, (_Float16)g0.y, (_Float16)g0.z, (_Float16)g0.w,
                       (_Float16)g1.x, (_Float16)g1.y, (_Float16)g1.z, (_Float16)g1.w};
      half8 b0 = *(const half8*)(&bT[((nw * 2) * 8 * 64 + ks * 64 + lane) * 8]);
      half8 b1 = *(const half8*)(&bT[((nw * 2 + 1) * 8 * 64 + ks * 64 + lane) * 8]);
      acc[0][0] = __builtin_amdgcn_mfma_f32_32x32x16_f16(a0, b0, acc[0][0], 0, 0, 0);
      acc[0][1] = __builtin_amdgcn_mfma_f32_32x32x16_f16(a0, b1, acc[0][1], 0, 0, 0);
      acc[1][0] = __builtin_amdgcn_mfma_f32_32x32x16_f16(a1, b0, acc[1][0], 0, 0, 0);
      acc[1][1] = __builtin_amdgcn_mfma_f32_32x32x16_f16(a1, b1, acc[1][1], 0, 0, 0);
    }
  }

  const int cn = n0 + nw * 64 + l31;
#pragma unroll
  for (int im = 0; im < 2; ++im)
#pragma unroll
    for (int in2 = 0; in2 < 2; ++in2)
#pragma unroll
      for (int reg = 0; reg < 16; ++reg) {
        int m = mw * 64 + im * 32 + (reg & 3) + 8 * (reg >> 2) + 4 * half;
        atomicAdd(out + (long long)m * OUT_F + cn + in2 * 32, acc[im][in2][reg]);
      }
}

extern "C" void kernel_launch(void* const* d_in, const int* in_sizes, int n_in,
                              void* d_out, int out_size, void* d_ws, size_t ws_size,
                              hipStream_t stream) {
  const float* x = (const float*)d_in[0];
  const int* qw = (const int*)d_in[1];
  const float* sc = (const float*)d_in[2];
  const int* qz = (const int*)d_in[3];
  const float* bias = (const float*)d_in[4];
  float* out = (float*)d_out;

  const size_t aT_bytes = (size_t)M_TOTAL * IN_F * sizeof(uint16_t);           // 2 MiB
  const size_t qT_bytes = (size_t)OUT_F * QW_COLS * sizeof(uint32_t);          // 32 MiB
  const size_t part_bytes = (size_t)KSPLIT * M_TOTAL * OUT_F * sizeof(float);  // 32 MiB
  uint16_t* aT = (uint16_t*)d_ws;
  uint32_t* qT = (uint32_t*)((char*)d_ws + aT_bytes);
  float* part = (float*)((char*)d_ws + aT_bytes + qT_bytes);

  if (ws_size >= aT_bytes + qT_bytes + part_bytes) {
    transpose_qw<<<2048, 256, 0, stream>>>((const uint32_t*)qw, qT);
    prologue<<<(M_TOTAL * IN_F) / (256 * 8), 256, 0, stream>>>(x, aT);
    awq_fast<<<NTILES * KSPLIT, 512, 0, stream>>>(aT, qT, sc, qz, part);
    reduce_out<<<(M_TOTAL * OUT_F) / (256 * 4), 256, 0, stream>>>(part, bias, out);
  } else {
    init_out<<<(M_TOTAL * OUT_F) / (256 * 4), 256, 0, stream>>>(bias, out);
    awq_fallback<<<FB_NTILES * 8, 256, 0, stream>>>(x, qw, sc, qz, out);
  }
}